// Round 7
// baseline (744.566 us; speedup 1.0000x reference)
//
#include <hip/hip_runtime.h>
#include <hip/hip_bf16.h>
#include <math.h>

#define IGNORE_INDEX (-100)

constexpr int BT = 2048, H = 4096, V = 32000;
constexpr int BM = 256, BN = 256, BK = 64;
constexpr int KT = H / BK;            // 64 k-tiles
constexpr int MT2 = BT / BM;          // 8
constexpr int NT2 = V / BN;           // 125
constexpr int NCHUNK = NT2 * 4;       // 500 partial chunks/row (64 cols each)

typedef __bf16 bf16x8 __attribute__((ext_vector_type(8)));
typedef float f32x4 __attribute__((ext_vector_type(4)));

__device__ __forceinline__ void gload_lds16(const __bf16* g, short* l) {
  __builtin_amdgcn_global_load_lds(
      (const __attribute__((address_space(1))) unsigned int*)(g),
      (__attribute__((address_space(3))) unsigned int*)(l), 16, 0, 0);
}

#define BAR()        asm volatile("s_barrier" ::: "memory")
#define WAIT_LGKM0() asm volatile("s_waitcnt lgkmcnt(0)" ::: "memory")
#define WAIT_VM(N)   asm volatile("s_waitcnt vmcnt(" #N ")" ::: "memory")

// ---------------------------------------------------------------------------
// fp32 -> bf16 bulk convert (used for X only; W converts inside the GEMM)
// ---------------------------------------------------------------------------
__global__ __launch_bounds__(256)
void convert_bf16(const float* __restrict__ src, __bf16* __restrict__ dst,
                  int n8) {
  int i = blockIdx.x * blockDim.x + threadIdx.x;
  const int stride = gridDim.x * blockDim.x;
  for (; i < n8; i += stride) {
    const float4 f0 = ((const float4*)src)[2 * i];
    const float4 f1 = ((const float4*)src)[2 * i + 1];
    bf16x8 v;
    v[0] = (__bf16)f0.x; v[1] = (__bf16)f0.y;
    v[2] = (__bf16)f0.z; v[3] = (__bf16)f0.w;
    v[4] = (__bf16)f1.x; v[5] = (__bf16)f1.y;
    v[6] = (__bf16)f1.z; v[7] = (__bf16)f1.w;
    ((bf16x8*)dst)[i] = v;
  }
}

// ---------------------------------------------------------------------------
// 256x256 GEMM on r4's verified skeleton (16x16x32 MFMA, [256][32] LDS
// regions with 2-bit quad XOR swizzle — measured conflict-free; 8 phases per
// 2 K-tiles, 1 barrier/phase). NEW: B (=W) is read in fp32 and converted
// in-kernel: reg-load (4x dwordx4) 2 phases ahead -> cast -> ds_write_b128
// into the SAME swizzled slots r4's DMA used, same phase slots, so the
// region read/overwrite audit is unchanged.
//   A-DMA drain discipline: A11@P2 drained by VM(6)@P4; A01@P6 by VM(6)@P8;
//   A00@P4 / A10@P8 drained as older-than side effects of the (compiler-
//   emitted) waits for B-reg loads consumed at P7 / next-P3 (vmcnt drains
//   oldest-first, so waiting on a newer load drains all older ones).
//   B write->read gaps >= 2 barriers; overwrite gaps >= 1 barrier. See r4.
// ---------------------------------------------------------------------------
__global__ __launch_bounds__(512, 2)
void gemm_lse_fz(const float* __restrict__ Wf,    // (V,H) fp32
                 const __bf16* __restrict__ Xb,   // (BT,H) bf16
                 const int* __restrict__ target,
                 const float* __restrict__ bias,
                 float* __restrict__ pM, float* __restrict__ pS,
                 float* __restrict__ gold)
{
  // flat: [buf][kh][256 rows][32 k-shorts]; buf stride 16384, kh stride 8192
  __shared__ short As[4 * 8192];
  __shared__ short Bs[4 * 8192];

  const int tid  = threadIdx.x;
  const int lane = tid & 63;
  const int wid  = tid >> 6;
  const int wr   = wid >> 2;        // 0..1 : rows [wr*128, +128)
  const int wcol = wid & 3;         // 0..3 : cols [wcol*64, +64)

  // XCD swizzle: nwg = 1000 = 8*125, bijective
  const int bid = (int)blockIdx.x;
  const int swz = (bid & 7) * 125 + (bid >> 3);
  const int mt = swz & (MT2 - 1);
  const int nt = swz >> 3;
  const int m0 = mt * BM, n0 = nt * BN;

  const int l15 = lane & 15;
  const int j4  = lane >> 4;
  // swizzle slot is lane-only: (row>>1)&3 == (l15>>1)&3 for all frag rows
  const int slotx = ((j4 ^ ((l15 >> 1) & 3)) & 3) << 3;      // shorts
  const int abase = (wr * 128 + l15) * 32 + slotx;
  const int bbase = (wcol * 64 + l15) * 32 + slotx;

  // A staging (DMA): lane covers row (l>>2), 16B slot (l&3); source
  // pre-swizzled so the linear LDS dest realizes the XOR layout
  const int srow = lane >> 2;
  const int sj8  = (((lane & 3) ^ ((lane >> 3) & 3)) << 3);

  const __bf16* ax0 = Xb + (size_t)(m0 + wid * 16 + srow) * H + sj8;
  const __bf16* ax1 = ax0 + (size_t)128 * H;

  // B reg-staging: lane covers row (l>>2), logical quad (l&3); the ds_write
  // goes DIRECTLY to the swizzled slot pq = (l&3)^((l>>3)&3)  (2-way banks).
  const float* wsrc0 = Wf + (size_t)(n0 + wid * 16 + (lane >> 2)) * H +
                       (lane & 3) * 8;
  const float* wsrc1 = wsrc0 + (size_t)128 * H;
  const int bwoff = (wid * 16 + (lane >> 2)) * 32 +
                    (((lane & 3) ^ ((lane >> 3) & 3)) << 3);

  f32x4 acc[8][4] = {};
  bf16x8 af[4], bfr[4];
  float4 rba[4], rbb[4];            // two alternating B-load reg sets

#define STAGE_A(BUF, KH, DT)                                                  \
  { gload_lds16(ax0 + (DT) * BK + (KH) * 32,                                  \
                &As[(BUF) * 16384 + (KH) * 8192 + wid * 512]);                \
    gload_lds16(ax1 + (DT) * BK + (KH) * 32,                                  \
                &As[(BUF) * 16384 + (KH) * 8192 + (8 + wid) * 512]); }

#define LOADB(RB, DT, KH)                                                     \
  { RB[0] = *(const float4*)(wsrc0 + (DT) * 64 + (KH) * 32);                  \
    RB[1] = *(const float4*)(wsrc0 + (DT) * 64 + (KH) * 32 + 4);              \
    RB[2] = *(const float4*)(wsrc1 + (DT) * 64 + (KH) * 32);                  \
    RB[3] = *(const float4*)(wsrc1 + (DT) * 64 + (KH) * 32 + 4); }

#define WRITEB(RB, BUF, KH)                                                   \
  { bf16x8 v0, v1;                                                            \
    v0[0] = (__bf16)RB[0].x; v0[1] = (__bf16)RB[0].y;                         \
    v0[2] = (__bf16)RB[0].z; v0[3] = (__bf16)RB[0].w;                         \
    v0[4] = (__bf16)RB[1].x; v0[5] = (__bf16)RB[1].y;                         \
    v0[6] = (__bf16)RB[1].z; v0[7] = (__bf16)RB[1].w;                         \
    v1[0] = (__bf16)RB[2].x; v1[1] = (__bf16)RB[2].y;                         \
    v1[2] = (__bf16)RB[2].z; v1[3] = (__bf16)RB[2].w;                         \
    v1[4] = (__bf16)RB[3].x; v1[5] = (__bf16)RB[3].y;                         \
    v1[6] = (__bf16)RB[3].z; v1[7] = (__bf16)RB[3].w;                         \
    *(bf16x8*)&Bs[(BUF) * 16384 + (KH) * 8192 + bwoff] = v0;                  \
    *(bf16x8*)&Bs[(BUF) * 16384 + (KH) * 8192 + bwoff + 4096] = v1; }

#define READ_A(BUF, KH, MH)                                                   \
  { _Pragma("unroll")                                                         \
    for (int mi = 0; mi < 4; ++mi)                                            \
      af[mi] = *(const bf16x8*)&As[(BUF) * 16384 + (KH) * 8192 + abase +      \
                                   (MH) * 2048 + mi * 512]; }

#define READ_B(BUF, KH)                                                       \
  { _Pragma("unroll")                                                         \
    for (int ni = 0; ni < 4; ++ni)                                            \
      bfr[ni] = *(const bf16x8*)&Bs[(BUF) * 16384 + (KH) * 8192 + bbase +     \
                                    ni * 512]; }

#define MFMA16(MH)                                                            \
  { __builtin_amdgcn_s_setprio(1);                                            \
    _Pragma("unroll")                                                         \
    for (int mi = 0; mi < 4; ++mi)                                            \
      _Pragma("unroll")                                                       \
      for (int ni = 0; ni < 4; ++ni)                                          \
        acc[(MH) * 4 + mi][ni] = __builtin_amdgcn_mfma_f32_16x16x32_bf16(     \
            af[mi], bfr[ni], acc[(MH) * 4 + mi][ni], 0, 0, 0);                \
    __builtin_amdgcn_s_setprio(0); }

  // ---- prologue: B00,B01,B10 reg-loaded+written; A00,A01,A10 DMA'd;
  // B11-loads (tile 1) left in flight in rbb. VM(4) drains all A-DMAs.
  {
    float4 rp0[4], rp1[4], rp2[4];
    LOADB(rp0, 0, 0); LOADB(rp1, 0, 1); LOADB(rp2, 1, 0);
    STAGE_A(0, 0, 0); STAGE_A(0, 1, 0); STAGE_A(1, 0, 1);
    WRITEB(rp0, 0, 0); WRITEB(rp1, 0, 1); WRITEB(rp2, 1, 0);
    LOADB(rbb, 1, 1);
    WAIT_VM(4);
  }
  BAR();

  // ---- main loop: 2 K-tiles/iter, 8 phases, 1 barrier each
  for (int t = 0; t <= KT - 4; t += 2) {
    // P1: compute (b0,k0,m0); issue B00'<-t+2 loads; write B11<-t+1
    LOADB(rba, 2, 0);
    WRITEB(rbb, 1, 1);
    READ_A(0, 0, 0); READ_B(0, 0);
    BAR(); WAIT_LGKM0(); MFMA16(0);
    // P2: (b0,k0,m1); DMA A11<-t+1
    STAGE_A(1, 1, 1);
    READ_A(0, 0, 1);
    BAR(); WAIT_LGKM0(); MFMA16(1);
    // P3: (b0,k1,m0); issue B01'<-t+2 loads; write B00<-t+2
    LOADB(rbb, 2, 1);
    WRITEB(rba, 0, 0);
    READ_A(0, 1, 0); READ_B(0, 1);
    BAR(); WAIT_LGKM0(); MFMA16(0);
    // P4: (b0,k1,m1); DMA A00<-t+2; VM(6) drains P2's A11 (read at P7)
    STAGE_A(0, 0, 2);
    WAIT_VM(6);
    READ_A(0, 1, 1);
    BAR(); WAIT_LGKM0(); MFMA16(1);
    // P5: (b1,k0,m0); issue B10'<-t+3 loads; write B01<-t+2
    LOADB(rba, 3, 0);
    WRITEB(rbb, 0, 1);
    READ_A(1, 0, 0); READ_B(1, 0);
    BAR(); WAIT_LGKM0(); MFMA16(0);
    // P6: (b1,k0,m1); DMA A01<-t+2
    STAGE_A(0, 1, 2);
    READ_A(1, 0, 1);
    BAR(); WAIT_LGKM0(); MFMA16(1);
    // P7: (b1,k1,m0); issue B11'<-t+3 loads; write B10<-t+3
    LOADB(rbb, 3, 1);
    WRITEB(rba, 1, 0);
    READ_A(1, 1, 0); READ_B(1, 1);
    BAR(); WAIT_LGKM0(); MFMA16(0);
    // P8: (b1,k1,m1); DMA A10<-t+3; VM(6) drains P6's A01 (read next-P3)
    STAGE_A(1, 0, 3);
    WAIT_VM(6);
    READ_A(1, 1, 1);
    BAR(); WAIT_LGKM0(); MFMA16(1);

    ax0 += 2 * BK; ax1 += 2 * BK; wsrc0 += 2 * 64; wsrc1 += 2 * 64;
  }

  // ---- tail: tiles KT-2 (buf0), KT-1 (buf1); rbb holds B11<-KT-1 loads
  WRITEB(rbb, 1, 1);
  READ_A(0, 0, 0); READ_B(0, 0);
  BAR(); WAIT_LGKM0(); MFMA16(0);
  STAGE_A(1, 1, 1);
  READ_A(0, 0, 1);
  BAR(); WAIT_LGKM0(); MFMA16(1);
  READ_A(0, 1, 0); READ_B(0, 1);
  BAR(); WAIT_LGKM0(); MFMA16(0);
  WAIT_VM(0);
  READ_A(0, 1, 1);
  BAR(); WAIT_LGKM0(); MFMA16(1);
  READ_A(1, 0, 0); READ_B(1, 0);
  BAR(); WAIT_LGKM0(); MFMA16(0);
  READ_A(1, 0, 1);
  BAR(); WAIT_LGKM0(); MFMA16(1);
  READ_A(1, 1, 0); READ_B(1, 1);
  BAR(); WAIT_LGKM0(); MFMA16(0);
  READ_A(1, 1, 1);
  WAIT_LGKM0(); MFMA16(1);

#undef STAGE_A
#undef LOADB
#undef WRITEB
#undef READ_A
#undef READ_B
#undef MFMA16

  // ---- epilogue: bias + per-row (max, sum-exp) over this wave's 64 cols
  const int g = lane >> 4;          // row group 0..3
  const int c = lane & 15;          // col-in-fragment
  const int colbase = n0 + wcol * 64;
  float bv[4];
#pragma unroll
  for (int ni = 0; ni < 4; ++ni) bv[ni] = bias[colbase + ni * 16 + c];

  const int chunk = nt * 4 + wcol;
#pragma unroll
  for (int mi = 0; mi < 8; ++mi) {
#pragma unroll
    for (int r = 0; r < 4; ++r) {
      const int row = m0 + wr * 128 + mi * 16 + g * 4 + r;
      const float v0 = acc[mi][0][r] + bv[0];
      const float v1 = acc[mi][1][r] + bv[1];
      const float v2 = acc[mi][2][r] + bv[2];
      const float v3 = acc[mi][3][r] + bv[3];
      float mx = fmaxf(fmaxf(v0, v1), fmaxf(v2, v3));
#pragma unroll
      for (int d = 1; d < 16; d <<= 1) mx = fmaxf(mx, __shfl_xor(mx, d));
      float s = expf(v0 - mx) + expf(v1 - mx) + expf(v2 - mx) + expf(v3 - mx);
#pragma unroll
      for (int d = 1; d < 16; d <<= 1) s += __shfl_xor(s, d);
      if (c == 0) {
        pM[(size_t)row * NCHUNK + chunk] = mx;
        pS[(size_t)row * NCHUNK + chunk] = s;
      }
      const int t = target[row];
      const int d0 = t - colbase;
      if (d0 >= 0 && d0 < 64 && c == (d0 & 15)) {
        const int nw = d0 >> 4;
        const float gv = (nw == 0) ? v0 : (nw == 1) ? v1 : (nw == 2) ? v2 : v3;
        gold[row] = gv;
      }
    }
  }
}

// one wave per row: combine 500 (max, sumexp) chunks -> rowterm
__global__ __launch_bounds__(256)
void reduce_lse(const float* __restrict__ pM, const float* __restrict__ pS,
                const float* __restrict__ gold, const int* __restrict__ target,
                const float* __restrict__ lw, float* __restrict__ rowterm)
{
  const int wid = threadIdx.x >> 6, lane = threadIdx.x & 63;
  const int row = blockIdx.x * 4 + wid;
  if (row >= BT) return;
  const float* pm = pM + (size_t)row * NCHUNK;
  const float* ps = pS + (size_t)row * NCHUNK;
  float m = -INFINITY;
  for (int c2 = lane; c2 < NCHUNK; c2 += 64) m = fmaxf(m, pm[c2]);
#pragma unroll
  for (int d = 1; d < 64; d <<= 1) m = fmaxf(m, __shfl_xor(m, d));
  float s = 0.f;
  for (int c2 = lane; c2 < NCHUNK; c2 += 64) s += ps[c2] * expf(pm[c2] - m);
#pragma unroll
  for (int d = 1; d < 64; d <<= 1) s += __shfl_xor(s, d);
  if (lane == 0) {
    const int t = target[row];
    float term = 0.f;
    if (t != IGNORE_INDEX) term = (m + logf(s) - gold[row]) * lw[row];
    rowterm[row] = term;
  }
}

// single-block deterministic finalize
__global__ __launch_bounds__(256)
void finalize(const float* __restrict__ rowterm, const int* __restrict__ target,
              const float* __restrict__ rsw, const int* __restrict__ gas,
              float* __restrict__ out)
{
  __shared__ float sred[4];
  __shared__ int cred[4];
  const int tid = threadIdx.x;
  float s = 0.f;
  int cnt = 0;
  for (int i = tid; i < BT; i += 256) {
    s += rowterm[i];
    cnt += (target[i] != IGNORE_INDEX) ? 1 : 0;
  }
#pragma unroll
  for (int d = 1; d < 64; d <<= 1) {
    s += __shfl_xor(s, d);
    cnt += __shfl_xor(cnt, d);
  }
  const int wid = tid >> 6, lane = tid & 63;
  if (lane == 0) { sred[wid] = s; cred[wid] = cnt; }
  __syncthreads();
  if (tid == 0) {
    const float st = sred[0] + sred[1] + sred[2] + sred[3];
    const int ct = cred[0] + cred[1] + cred[2] + cred[3];
    const float n = (float)((ct > 0) ? ct : 1);
    const float rs = rsw[0];
    float loss = (rs == 0.f) ? 0.f : (st / n) / rs;
    loss /= (float)gas[0];
    out[0] = loss;
  }
}

extern "C" void kernel_launch(void* const* d_in, const int* in_sizes, int n_in,
                              void* d_out, int out_size, void* d_ws, size_t ws_size,
                              hipStream_t stream)
{
  const float* Wt     = (const float*)d_in[0];  // lin_weight (V,H) fp32
  const float* X      = (const float*)d_in[1];  // _input (BT,H) fp32
  const int*   target = (const int*)d_in[2];
  const float* bias   = (const float*)d_in[3];
  const float* lw     = (const float*)d_in[4];
  const float* rsw    = (const float*)d_in[5];
  const int*   gas    = (const int*)d_in[6];
  float* out = (float*)d_out;

  const size_t nX = (size_t)BT * H;

  __bf16* Xb = (__bf16*)d_ws;
  float* pM = (float*)(Xb + nX);
  float* pS = pM + (size_t)BT * NCHUNK;
  float* gold = pS + (size_t)BT * NCHUNK;
  float* rowterm = gold + BT;

  convert_bf16<<<dim3(256), dim3(256), 0, stream>>>(X, Xb, (int)(nX / 8));
  gemm_lse_fz<<<dim3(MT2 * NT2), dim3(512), 0, stream>>>(Wt, Xb, target,
                                                         bias, pM, pS, gold);
  reduce_lse<<<dim3(BT / 4), dim3(256), 0, stream>>>(pM, pS, gold, target, lw,
                                                     rowterm);
  finalize<<<dim3(1), dim3(256), 0, stream>>>(rowterm, target, rsw, gas, out);
}

// Round 8
// 684.653 us; speedup vs baseline: 1.0875x; 1.0875x over previous
//
#include <hip/hip_runtime.h>
#include <hip/hip_bf16.h>
#include <math.h>

#define IGNORE_INDEX (-100)

constexpr int BT = 2048, H = 4096, V = 32000;
constexpr int BM = 256, BN = 256, BK = 64;
constexpr int KT = H / BK;            // 64 k-tiles
constexpr int MT2 = BT / BM;          // 8
constexpr int NT2 = V / BN;           // 125
constexpr int NCHUNK = NT2 * 4;       // 500 partial chunks/row (64 cols each)

typedef __bf16 bf16x8 __attribute__((ext_vector_type(8)));
typedef float f32x4 __attribute__((ext_vector_type(4)));

__device__ __forceinline__ void gload_lds16(const __bf16* g, short* l) {
  __builtin_amdgcn_global_load_lds(
      (const __attribute__((address_space(1))) unsigned int*)(g),
      (__attribute__((address_space(3))) unsigned int*)(l), 16, 0, 0);
}

#define BAR()        asm volatile("s_barrier" ::: "memory")
#define WAIT_VM(N)   asm volatile("s_waitcnt vmcnt(" #N ")" ::: "memory")
#define SB0()        __builtin_amdgcn_sched_barrier(0)

// ---------------------------------------------------------------------------
// fp32 -> bf16 bulk convert
// ---------------------------------------------------------------------------
__global__ __launch_bounds__(256)
void convert_bf16(const float* __restrict__ src, __bf16* __restrict__ dst,
                  int n8) {
  int i = blockIdx.x * blockDim.x + threadIdx.x;
  const int stride = gridDim.x * blockDim.x;
  for (; i < n8; i += stride) {
    const float4 f0 = ((const float4*)src)[2 * i];
    const float4 f1 = ((const float4*)src)[2 * i + 1];
    bf16x8 v;
    v[0] = (__bf16)f0.x; v[1] = (__bf16)f0.y;
    v[2] = (__bf16)f0.z; v[3] = (__bf16)f0.w;
    v[4] = (__bf16)f1.x; v[5] = (__bf16)f1.y;
    v[6] = (__bf16)f1.z; v[7] = (__bf16)f1.w;
    ((bf16x8*)dst)[i] = v;
  }
}

// ---------------------------------------------------------------------------
// r4's verified 256x256 8-phase 1-barrier GEMM, with the forced lgkmcnt(0)
// REMOVED: the compiler's counted lgkm waits let LDS-read service overlap
// the MFMA cluster (separate pipes). sched_barrier(0) before each s_barrier
// pins MFMA + memory ops into their phase window (rule #18 fence), keeping
// r4's audited overwrite-after-read discipline:
//   reads(p) complete before MFMA(p) [hw counted wait], MFMA(p) pinned
//   before BAR(p+1) [SB0], stages(p+2) issue after BAR(p+1) -> no wave can
//   see a DMA overwrite race. VM plan identical to r4.
// ---------------------------------------------------------------------------
__global__ __launch_bounds__(512, 2)
void gemm_lse_8ph(const __bf16* __restrict__ Wb,   // (V,H) bf16
                  const __bf16* __restrict__ Xb,   // (BT,H) bf16
                  const int* __restrict__ target,
                  const float* __restrict__ bias,
                  float* __restrict__ pM, float* __restrict__ pS,
                  float* __restrict__ gold)
{
  // flat: [buf][kh][256 rows][32 k-shorts]; buf stride 16384, kh stride 8192
  __shared__ short As[4 * 8192];
  __shared__ short Bs[4 * 8192];

  const int tid  = threadIdx.x;
  const int lane = tid & 63;
  const int wid  = tid >> 6;
  const int wr   = wid >> 2;        // 0..1 : rows [wr*128, +128)
  const int wcol = wid & 3;         // 0..3 : cols [wcol*64, +64)

  // XCD swizzle: nwg = 1000 = 8*125, bijective
  const int bid = (int)blockIdx.x;
  const int swz = (bid & 7) * 125 + (bid >> 3);
  const int mt = swz & (MT2 - 1);
  const int nt = swz >> 3;
  const int m0 = mt * BM, n0 = nt * BN;

  const int l15 = lane & 15;
  const int j4  = lane >> 4;
  // swizzle slot is lane-only: (row>>1)&3 == (l15>>1)&3 for all frag rows
  const int slotx = ((j4 ^ ((l15 >> 1) & 3)) & 3) << 3;      // shorts
  const int abase = (wr * 128 + l15) * 32 + slotx;
  const int bbase = (wcol * 64 + l15) * 32 + slotx;

  // staging: lane covers row (l>>2), 16B slot (l&3); source pre-swizzled
  const int srow = lane >> 2;
  const int sj8  = (((lane & 3) ^ ((lane >> 3) & 3)) << 3);

  const __bf16* ax0 = Xb + (size_t)(m0 + wid * 16 + srow) * H + sj8;
  const __bf16* ax1 = ax0 + (size_t)128 * H;
  const __bf16* bx0 = Wb + (size_t)(n0 + wid * 16 + srow) * H + sj8;
  const __bf16* bx1 = bx0 + (size_t)128 * H;

  f32x4 acc[8][4] = {};
  bf16x8 af[4], bfr[4];

#define STAGE_A(BUF, KH, DT)                                                  \
  { gload_lds16(ax0 + (DT) * BK + (KH) * 32,                                  \
                &As[(BUF) * 16384 + (KH) * 8192 + wid * 512]);                \
    gload_lds16(ax1 + (DT) * BK + (KH) * 32,                                  \
                &As[(BUF) * 16384 + (KH) * 8192 + (8 + wid) * 512]); }

#define STAGE_B(BUF, KH, DT)                                                  \
  { gload_lds16(bx0 + (DT) * BK + (KH) * 32,                                  \
                &Bs[(BUF) * 16384 + (KH) * 8192 + wid * 512]);                \
    gload_lds16(bx1 + (DT) * BK + (KH) * 32,                                  \
                &Bs[(BUF) * 16384 + (KH) * 8192 + (8 + wid) * 512]); }

#define READ_A(BUF, KH, MH)                                                   \
  { _Pragma("unroll")                                                         \
    for (int mi = 0; mi < 4; ++mi)                                            \
      af[mi] = *(const bf16x8*)&As[(BUF) * 16384 + (KH) * 8192 + abase +      \
                                   (MH) * 2048 + mi * 512]; }

#define READ_B(BUF, KH)                                                       \
  { _Pragma("unroll")                                                         \
    for (int ni = 0; ni < 4; ++ni)                                            \
      bfr[ni] = *(const bf16x8*)&Bs[(BUF) * 16384 + (KH) * 8192 + bbase +     \
                                    ni * 512]; }

#define MFMA16(MH)                                                            \
  { __builtin_amdgcn_s_setprio(1);                                            \
    _Pragma("unroll")                                                         \
    for (int mi = 0; mi < 4; ++mi)                                            \
      _Pragma("unroll")                                                       \
      for (int ni = 0; ni < 4; ++ni)                                          \
        acc[(MH) * 4 + mi][ni] = __builtin_amdgcn_mfma_f32_16x16x32_bf16(     \
            af[mi], bfr[ni], acc[(MH) * 4 + mi][ni], 0, 0, 0);                \
    __builtin_amdgcn_s_setprio(0); }

  // ---- prologue: tile0 fully + tile1 k0.  VM(4) leaves {B10,A10} in flight
  STAGE_B(0, 0, 0); STAGE_A(0, 0, 0); STAGE_B(0, 1, 0); STAGE_A(0, 1, 0);
  STAGE_B(1, 0, 1); STAGE_A(1, 0, 1);
  WAIT_VM(4);
  BAR();

  // ---- main loop: 2 K-tiles/iter, 8 phases, 1 barrier each
  for (int t = 0; t <= KT - 4; t += 2) {
    // P1: compute t(k0,mh0); stage B11 <- (t+1).k1
    READ_A(0, 0, 0); READ_B(0, 0); STAGE_B(1, 1, 1);
    SB0(); BAR(); MFMA16(0);
    // P2: t(k0,mh1); stage A11 <- (t+1).k1
    READ_A(0, 0, 1); STAGE_A(1, 1, 1);
    SB0(); BAR(); MFMA16(1);
    // P3: t(k1,mh0); stage B00 <- (t+2).k0
    READ_A(0, 1, 0); READ_B(0, 1); STAGE_B(0, 0, 2);
    SB0(); BAR(); MFMA16(0);
    // P4: t(k1,mh1); stage A00 <- (t+2).k0; VM(4) drains through P2's A11
    READ_A(0, 1, 1); STAGE_A(0, 0, 2);
    WAIT_VM(4); SB0(); BAR(); MFMA16(1);
    // P5: t+1(k0,mh0); stage B01 <- (t+2).k1
    READ_A(1, 0, 0); READ_B(1, 0); STAGE_B(0, 1, 2);
    SB0(); BAR(); MFMA16(0);
    // P6: t+1(k0,mh1); stage A01 <- (t+2).k1
    READ_A(1, 0, 1); STAGE_A(0, 1, 2);
    SB0(); BAR(); MFMA16(1);
    // P7: t+1(k1,mh0); stage B10 <- (t+3).k0
    READ_A(1, 1, 0); READ_B(1, 1); STAGE_B(1, 0, 3);
    SB0(); BAR(); MFMA16(0);
    // P8: t+1(k1,mh1); stage A10 <- (t+3).k0; VM(4) drains through P6's A01
    READ_A(1, 1, 1); STAGE_A(1, 0, 3);
    WAIT_VM(4); SB0(); BAR(); MFMA16(1);

    ax0 += 2 * BK; ax1 += 2 * BK; bx0 += 2 * BK; bx1 += 2 * BK;
  }

  // ---- tail: tiles KT-2 (buf0), KT-1 (buf1); stage only B11/A11 <- KT-1.k1
  READ_A(0, 0, 0); READ_B(0, 0); STAGE_B(1, 1, 1);
  SB0(); BAR(); MFMA16(0);
  READ_A(0, 0, 1); STAGE_A(1, 1, 1);
  SB0(); BAR(); MFMA16(1);
  READ_A(0, 1, 0); READ_B(0, 1);
  MFMA16(0);
  READ_A(0, 1, 1);
  WAIT_VM(0); SB0(); BAR(); MFMA16(1);
  READ_A(1, 0, 0); READ_B(1, 0);
  MFMA16(0);
  READ_A(1, 0, 1);
  MFMA16(1);
  READ_A(1, 1, 0); READ_B(1, 1);
  MFMA16(0);
  READ_A(1, 1, 1);
  MFMA16(1);

#undef STAGE_A
#undef STAGE_B
#undef READ_A
#undef READ_B
#undef MFMA16

  // ---- epilogue: bias + per-row (max, sum-exp) over this wave's 64 cols
  const int g = lane >> 4;          // row group 0..3
  const int c = lane & 15;          // col-in-fragment
  const int colbase = n0 + wcol * 64;
  float bv[4];
#pragma unroll
  for (int ni = 0; ni < 4; ++ni) bv[ni] = bias[colbase + ni * 16 + c];

  const int chunk = nt * 4 + wcol;
#pragma unroll
  for (int mi = 0; mi < 8; ++mi) {
#pragma unroll
    for (int r = 0; r < 4; ++r) {
      const int row = m0 + wr * 128 + mi * 16 + g * 4 + r;
      const float v0 = acc[mi][0][r] + bv[0];
      const float v1 = acc[mi][1][r] + bv[1];
      const float v2 = acc[mi][2][r] + bv[2];
      const float v3 = acc[mi][3][r] + bv[3];
      float mx = fmaxf(fmaxf(v0, v1), fmaxf(v2, v3));
#pragma unroll
      for (int d = 1; d < 16; d <<= 1) mx = fmaxf(mx, __shfl_xor(mx, d));
      float s = expf(v0 - mx) + expf(v1 - mx) + expf(v2 - mx) + expf(v3 - mx);
#pragma unroll
      for (int d = 1; d < 16; d <<= 1) s += __shfl_xor(s, d);
      if (c == 0) {
        pM[(size_t)row * NCHUNK + chunk] = mx;
        pS[(size_t)row * NCHUNK + chunk] = s;
      }
      const int t = target[row];
      const int d0 = t - colbase;
      if (d0 >= 0 && d0 < 64 && c == (d0 & 15)) {
        const int nw = d0 >> 4;
        const float gv = (nw == 0) ? v0 : (nw == 1) ? v1 : (nw == 2) ? v2 : v3;
        gold[row] = gv;
      }
    }
  }
}

// one wave per row: combine 500 (max, sumexp) chunks -> rowterm
__global__ __launch_bounds__(256)
void reduce_lse(const float* __restrict__ pM, const float* __restrict__ pS,
                const float* __restrict__ gold, const int* __restrict__ target,
                const float* __restrict__ lw, float* __restrict__ rowterm)
{
  const int wid = threadIdx.x >> 6, lane = threadIdx.x & 63;
  const int row = blockIdx.x * 4 + wid;
  if (row >= BT) return;
  const float* pm = pM + (size_t)row * NCHUNK;
  const float* ps = pS + (size_t)row * NCHUNK;
  float m = -INFINITY;
  for (int c2 = lane; c2 < NCHUNK; c2 += 64) m = fmaxf(m, pm[c2]);
#pragma unroll
  for (int d = 1; d < 64; d <<= 1) m = fmaxf(m, __shfl_xor(m, d));
  float s = 0.f;
  for (int c2 = lane; c2 < NCHUNK; c2 += 64) s += ps[c2] * expf(pm[c2] - m);
#pragma unroll
  for (int d = 1; d < 64; d <<= 1) s += __shfl_xor(s, d);
  if (lane == 0) {
    const int t = target[row];
    float term = 0.f;
    if (t != IGNORE_INDEX) term = (m + logf(s) - gold[row]) * lw[row];
    rowterm[row] = term;
  }
}

// single-block deterministic finalize
__global__ __launch_bounds__(256)
void finalize(const float* __restrict__ rowterm, const int* __restrict__ target,
              const float* __restrict__ rsw, const int* __restrict__ gas,
              float* __restrict__ out)
{
  __shared__ float sred[4];
  __shared__ int cred[4];
  const int tid = threadIdx.x;
  float s = 0.f;
  int cnt = 0;
  for (int i = tid; i < BT; i += 256) {
    s += rowterm[i];
    cnt += (target[i] != IGNORE_INDEX) ? 1 : 0;
  }
#pragma unroll
  for (int d = 1; d < 64; d <<= 1) {
    s += __shfl_xor(s, d);
    cnt += __shfl_xor(cnt, d);
  }
  const int wid = tid >> 6, lane = tid & 63;
  if (lane == 0) { sred[wid] = s; cred[wid] = cnt; }
  __syncthreads();
  if (tid == 0) {
    const float st = sred[0] + sred[1] + sred[2] + sred[3];
    const int ct = cred[0] + cred[1] + cred[2] + cred[3];
    const float n = (float)((ct > 0) ? ct : 1);
    const float rs = rsw[0];
    float loss = (rs == 0.f) ? 0.f : (st / n) / rs;
    loss /= (float)gas[0];
    out[0] = loss;
  }
}

extern "C" void kernel_launch(void* const* d_in, const int* in_sizes, int n_in,
                              void* d_out, int out_size, void* d_ws, size_t ws_size,
                              hipStream_t stream)
{
  const float* Wt     = (const float*)d_in[0];  // lin_weight (V,H)
  const float* X      = (const float*)d_in[1];  // _input (BT,H)
  const int*   target = (const int*)d_in[2];
  const float* bias   = (const float*)d_in[3];
  const float* lw     = (const float*)d_in[4];
  const float* rsw    = (const float*)d_in[5];
  const int*   gas    = (const int*)d_in[6];
  float* out = (float*)d_out;

  const size_t nW = (size_t)V * H, nX = (size_t)BT * H;

  __bf16* Wb = (__bf16*)d_ws;
  __bf16* Xb = Wb + nW;
  float* pM = (float*)(Xb + nX);
  float* pS = pM + (size_t)BT * NCHUNK;
  float* gold = pS + (size_t)BT * NCHUNK;
  float* rowterm = gold + BT;

  convert_bf16<<<dim3(2048), dim3(256), 0, stream>>>(Wt, Wb, (int)(nW / 8));
  convert_bf16<<<dim3(256), dim3(256), 0, stream>>>(X, Xb, (int)(nX / 8));
  gemm_lse_8ph<<<dim3(MT2 * NT2), dim3(512), 0, stream>>>(Wb, Xb, target,
                                                          bias, pM, pS, gold);
  reduce_lse<<<dim3(BT / 4), dim3(256), 0, stream>>>(pM, pS, gold, target, lw,
                                                     rowterm);
  finalize<<<dim3(1), dim3(256), 0, stream>>>(rowterm, target, rsw, gas, out);
}

// Round 9
// 676.141 us; speedup vs baseline: 1.1012x; 1.0126x over previous
//
#include <hip/hip_runtime.h>
#include <hip/hip_bf16.h>
#include <math.h>

#define IGNORE_INDEX (-100)

constexpr int BT = 2048, H = 4096, V = 32000;
constexpr int BM = 256, BN = 256, BK = 64;
constexpr int KT = H / BK;            // 64 k-tiles
constexpr int MT2 = BT / BM;          // 8
constexpr int NT2 = V / BN;           // 125
constexpr int NCHUNK = NT2 * 4;       // 500 partial chunks/row (64 cols each)

typedef __bf16 bf16x8 __attribute__((ext_vector_type(8)));
typedef float f32x4 __attribute__((ext_vector_type(4)));

__device__ __forceinline__ void gload_lds16(const __bf16* g, short* l) {
  __builtin_amdgcn_global_load_lds(
      (const __attribute__((address_space(1))) unsigned int*)(g),
      (__attribute__((address_space(3))) unsigned int*)(l), 16, 0, 0);
}

#define BAR()        asm volatile("s_barrier" ::: "memory")
#define WAIT_VM(N)   asm volatile("s_waitcnt vmcnt(" #N ")" ::: "memory")
#define SB0()        __builtin_amdgcn_sched_barrier(0)

// ---------------------------------------------------------------------------
// fp32 -> bf16 bulk convert
// ---------------------------------------------------------------------------
__global__ __launch_bounds__(256)
void convert_bf16(const float* __restrict__ src, __bf16* __restrict__ dst,
                  int n8) {
  int i = blockIdx.x * blockDim.x + threadIdx.x;
  const int stride = gridDim.x * blockDim.x;
  for (; i < n8; i += stride) {
    const float4 f0 = ((const float4*)src)[2 * i];
    const float4 f1 = ((const float4*)src)[2 * i + 1];
    bf16x8 v;
    v[0] = (__bf16)f0.x; v[1] = (__bf16)f0.y;
    v[2] = (__bf16)f0.z; v[3] = (__bf16)f0.w;
    v[4] = (__bf16)f1.x; v[5] = (__bf16)f1.y;
    v[6] = (__bf16)f1.z; v[7] = (__bf16)f1.w;
    ((bf16x8*)dst)[i] = v;
  }
}

// ---------------------------------------------------------------------------
// r4/r8 skeleton + ONE-PHASE-AHEAD ds_read pipeline:
// phase p = [STAGE; VM?; issue reads for p+1 (alt reg set); SB0; BAR;
//            MFMA consuming reads issued at p-1].
// Region audit (stage at p needs all waves past BAR(p-1); read@q forced
// serviced before MFMA(q+1) < BAR(q+2) => stage safe iff p-1 >= q+2):
//   A(b0k0): reads P8',P1 -> stage P4 ✓   B(b0k0): read P8' -> stage P3 ✓
//   A(b0k1): reads P2,P3  -> stage P6 ✓   B(b0k1): read P2  -> stage P5 ✓
//   A(b1k0): reads P4,P5  -> stage P8 ✓   B(b1k0): read P4  -> stage P7 ✓
//   A(b1k1): reads P6,P7  -> stage P2' ✓  B(b1k1): read P6  -> stage P1' ✓
// DMA landing (vmcnt, ds_reads excluded): VM(4)@P4 drains prevP7,prevP8,
// P1,P2 (b1 regions before P4/P5 reads ✓); VM(4)@P8 drains P3..P6 (b0 t+2
// regions before P8/P2' reads ✓). Reads issue AFTER the VM wait in-phase.
// ---------------------------------------------------------------------------
__global__ __launch_bounds__(512, 2)
void gemm_lse_pipe(const __bf16* __restrict__ Wb,   // (V,H) bf16
                   const __bf16* __restrict__ Xb,   // (BT,H) bf16
                   const int* __restrict__ target,
                   const float* __restrict__ bias,
                   float* __restrict__ pM, float* __restrict__ pS,
                   float* __restrict__ gold)
{
  // flat: [buf][kh][256 rows][32 k-shorts]; buf stride 16384, kh stride 8192
  __shared__ short As[4 * 8192];
  __shared__ short Bs[4 * 8192];

  const int tid  = threadIdx.x;
  const int lane = tid & 63;
  const int wid  = tid >> 6;
  const int wr   = wid >> 2;        // 0..1 : rows [wr*128, +128)
  const int wcol = wid & 3;         // 0..3 : cols [wcol*64, +64)

  // XCD swizzle: nwg = 1000 = 8*125, bijective
  const int bid = (int)blockIdx.x;
  const int swz = (bid & 7) * 125 + (bid >> 3);
  const int mt = swz & (MT2 - 1);
  const int nt = swz >> 3;
  const int m0 = mt * BM, n0 = nt * BN;

  const int l15 = lane & 15;
  const int j4  = lane >> 4;
  // swizzle slot is lane-only: (row>>1)&3 == (l15>>1)&3 for all frag rows
  const int slotx = ((j4 ^ ((l15 >> 1) & 3)) & 3) << 3;      // shorts
  const int abase = (wr * 128 + l15) * 32 + slotx;
  const int bbase = (wcol * 64 + l15) * 32 + slotx;

  // staging: lane covers row (l>>2), 16B slot (l&3); source pre-swizzled
  const int srow = lane >> 2;
  const int sj8  = (((lane & 3) ^ ((lane >> 3) & 3)) << 3);

  const __bf16* ax0 = Xb + (size_t)(m0 + wid * 16 + srow) * H + sj8;
  const __bf16* ax1 = ax0 + (size_t)128 * H;
  const __bf16* bx0 = Wb + (size_t)(n0 + wid * 16 + srow) * H + sj8;
  const __bf16* bx1 = bx0 + (size_t)128 * H;

  f32x4 acc[8][4] = {};
  bf16x8 a0[4], a1[4], b0r[4], b1r[4];   // double-buffered fragment sets

#define STAGE_A(BUF, KH, DT)                                                  \
  { gload_lds16(ax0 + (DT) * BK + (KH) * 32,                                  \
                &As[(BUF) * 16384 + (KH) * 8192 + wid * 512]);                \
    gload_lds16(ax1 + (DT) * BK + (KH) * 32,                                  \
                &As[(BUF) * 16384 + (KH) * 8192 + (8 + wid) * 512]); }

#define STAGE_B(BUF, KH, DT)                                                  \
  { gload_lds16(bx0 + (DT) * BK + (KH) * 32,                                  \
                &Bs[(BUF) * 16384 + (KH) * 8192 + wid * 512]);                \
    gload_lds16(bx1 + (DT) * BK + (KH) * 32,                                  \
                &Bs[(BUF) * 16384 + (KH) * 8192 + (8 + wid) * 512]); }

#define RD_A(DST, BUF, KH, MH)                                                \
  { _Pragma("unroll")                                                         \
    for (int mi = 0; mi < 4; ++mi)                                            \
      DST[mi] = *(const bf16x8*)&As[(BUF) * 16384 + (KH) * 8192 + abase +     \
                                    (MH) * 2048 + mi * 512]; }

#define RD_B(DST, BUF, KH)                                                    \
  { _Pragma("unroll")                                                         \
    for (int ni = 0; ni < 4; ++ni)                                            \
      DST[ni] = *(const bf16x8*)&Bs[(BUF) * 16384 + (KH) * 8192 + bbase +     \
                                    ni * 512]; }

#define MF(ASET, BSET, MH)                                                    \
  { __builtin_amdgcn_s_setprio(1);                                            \
    _Pragma("unroll")                                                         \
    for (int mi = 0; mi < 4; ++mi)                                            \
      _Pragma("unroll")                                                       \
      for (int ni = 0; ni < 4; ++ni)                                          \
        acc[(MH) * 4 + mi][ni] = __builtin_amdgcn_mfma_f32_16x16x32_bf16(     \
            ASET[mi], BSET[ni], acc[(MH) * 4 + mi][ni], 0, 0, 0);             \
    __builtin_amdgcn_s_setprio(0); }

  // ---- prologue: tile0 fully + tile1 k0. 12 loads; VM(4) drains the 8 of
  // tile0 (b0 valid), leaves {B10,A10} (4) in flight. First read set issued
  // pre-BAR, matching steady state.
  STAGE_B(0, 0, 0); STAGE_A(0, 0, 0); STAGE_B(0, 1, 0); STAGE_A(0, 1, 0);
  STAGE_B(1, 0, 1); STAGE_A(1, 0, 1);
  WAIT_VM(4);
  RD_A(a0, 0, 0, 0); RD_B(b0r, 0, 0);
  SB0(); BAR();

  // ---- main loop: 2 K-tiles/iter, 8 phases, 1 barrier each, reads 1 ahead
  for (int t = 0; t <= KT - 4; t += 2) {
    // P1: stage B11<-t+1; read A(b0,k0,m1); compute (b0,k0,mh0)
    STAGE_B(1, 1, 1);
    RD_A(a1, 0, 0, 1);
    SB0(); BAR(); MF(a0, b0r, 0);
    // P2: stage A11<-t+1; read A(b0,k1,m0)+B(b0,k1); compute (b0,k0,mh1)
    STAGE_A(1, 1, 1);
    RD_A(a0, 0, 1, 0); RD_B(b1r, 0, 1);
    SB0(); BAR(); MF(a1, b0r, 1);
    // P3: stage B00<-t+2; read A(b0,k1,m1); compute (b0,k1,mh0)
    STAGE_B(0, 0, 2);
    RD_A(a1, 0, 1, 1);
    SB0(); BAR(); MF(a0, b1r, 0);
    // P4: stage A00<-t+2; VM(4); read A(b1,k0,m0)+B(b1,k0); compute (b0,k1,mh1)
    STAGE_A(0, 0, 2);
    WAIT_VM(4);
    RD_A(a0, 1, 0, 0); RD_B(b0r, 1, 0);
    SB0(); BAR(); MF(a1, b1r, 1);
    // P5: stage B01<-t+2; read A(b1,k0,m1); compute (b1,k0,mh0)
    STAGE_B(0, 1, 2);
    RD_A(a1, 1, 0, 1);
    SB0(); BAR(); MF(a0, b0r, 0);
    // P6: stage A01<-t+2; read A(b1,k1,m0)+B(b1,k1); compute (b1,k0,mh1)
    STAGE_A(0, 1, 2);
    RD_A(a0, 1, 1, 0); RD_B(b1r, 1, 1);
    SB0(); BAR(); MF(a1, b0r, 1);
    // P7: stage B10<-t+3; read A(b1,k1,m1); compute (b1,k1,mh0)
    STAGE_B(1, 0, 3);
    RD_A(a1, 1, 1, 1);
    SB0(); BAR(); MF(a0, b1r, 0);
    // P8: stage A10<-t+3; VM(4) (drains P3..P6 -> b0 t+2 valid);
    //     read A(b0,k0,m0)+B(b0,k0) of t+2; compute (b1,k1,mh1)
    STAGE_A(1, 0, 3);
    WAIT_VM(4);
    RD_A(a0, 0, 0, 0); RD_B(b0r, 0, 0);
    SB0(); BAR(); MF(a1, b1r, 1);

    ax0 += 2 * BK; ax1 += 2 * BK; bx0 += 2 * BK; bx1 += 2 * BK;
  }

  // ---- tail: tiles KT-2 (b0), KT-1 (b1); stage only B11/A11 <- KT-1.k1
  STAGE_B(1, 1, 1);
  RD_A(a1, 0, 0, 1);
  SB0(); BAR(); MF(a0, b0r, 0);
  STAGE_A(1, 1, 1);
  RD_A(a0, 0, 1, 0); RD_B(b1r, 0, 1);
  SB0(); BAR(); MF(a1, b0r, 1);
  RD_A(a1, 0, 1, 1);
  SB0(); BAR(); MF(a0, b1r, 0);
  WAIT_VM(4);                       // drains loop P7,P8 -> b1k0 valid
  RD_A(a0, 1, 0, 0); RD_B(b0r, 1, 0);
  SB0(); BAR(); MF(a1, b1r, 1);
  RD_A(a1, 1, 0, 1);
  SB0(); BAR(); MF(a0, b0r, 0);
  WAIT_VM(0);                       // drains T1,T2 -> b1k1 (KT-1.k1) valid
  RD_A(a0, 1, 1, 0); RD_B(b1r, 1, 1);
  SB0(); BAR(); MF(a1, b0r, 1);
  RD_A(a1, 1, 1, 1);
  SB0(); BAR(); MF(a0, b1r, 0);
  MF(a1, b1r, 1);

#undef STAGE_A
#undef STAGE_B
#undef RD_A
#undef RD_B
#undef MF

  // ---- epilogue: bias + per-row (max, sum-exp) over this wave's 64 cols
  const int g = lane >> 4;          // row group 0..3
  const int c = lane & 15;          // col-in-fragment
  const int colbase = n0 + wcol * 64;
  float bv[4];
#pragma unroll
  for (int ni = 0; ni < 4; ++ni) bv[ni] = bias[colbase + ni * 16 + c];

  const int chunk = nt * 4 + wcol;
#pragma unroll
  for (int mi = 0; mi < 8; ++mi) {
#pragma unroll
    for (int r = 0; r < 4; ++r) {
      const int row = m0 + wr * 128 + mi * 16 + g * 4 + r;
      const float v0 = acc[mi][0][r] + bv[0];
      const float v1 = acc[mi][1][r] + bv[1];
      const float v2 = acc[mi][2][r] + bv[2];
      const float v3 = acc[mi][3][r] + bv[3];
      float mx = fmaxf(fmaxf(v0, v1), fmaxf(v2, v3));
#pragma unroll
      for (int d = 1; d < 16; d <<= 1) mx = fmaxf(mx, __shfl_xor(mx, d));
      float s = expf(v0 - mx) + expf(v1 - mx) + expf(v2 - mx) + expf(v3 - mx);
#pragma unroll
      for (int d = 1; d < 16; d <<= 1) s += __shfl_xor(s, d);
      if (c == 0) {
        pM[(size_t)row * NCHUNK + chunk] = mx;
        pS[(size_t)row * NCHUNK + chunk] = s;
      }
      const int t = target[row];
      const int d0 = t - colbase;
      if (d0 >= 0 && d0 < 64 && c == (d0 & 15)) {
        const int nw = d0 >> 4;
        const float gv = (nw == 0) ? v0 : (nw == 1) ? v1 : (nw == 2) ? v2 : v3;
        gold[row] = gv;
      }
    }
  }
}

// one wave per row: combine 500 (max, sumexp) chunks -> rowterm
__global__ __launch_bounds__(256)
void reduce_lse(const float* __restrict__ pM, const float* __restrict__ pS,
                const float* __restrict__ gold, const int* __restrict__ target,
                const float* __restrict__ lw, float* __restrict__ rowterm)
{
  const int wid = threadIdx.x >> 6, lane = threadIdx.x & 63;
  const int row = blockIdx.x * 4 + wid;
  if (row >= BT) return;
  const float* pm = pM + (size_t)row * NCHUNK;
  const float* ps = pS + (size_t)row * NCHUNK;
  float m = -INFINITY;
  for (int c2 = lane; c2 < NCHUNK; c2 += 64) m = fmaxf(m, pm[c2]);
#pragma unroll
  for (int d = 1; d < 64; d <<= 1) m = fmaxf(m, __shfl_xor(m, d));
  float s = 0.f;
  for (int c2 = lane; c2 < NCHUNK; c2 += 64) s += ps[c2] * expf(pm[c2] - m);
#pragma unroll
  for (int d = 1; d < 64; d <<= 1) s += __shfl_xor(s, d);
  if (lane == 0) {
    const int t = target[row];
    float term = 0.f;
    if (t != IGNORE_INDEX) term = (m + logf(s) - gold[row]) * lw[row];
    rowterm[row] = term;
  }
}

// single-block deterministic finalize
__global__ __launch_bounds__(256)
void finalize(const float* __restrict__ rowterm, const int* __restrict__ target,
              const float* __restrict__ rsw, const int* __restrict__ gas,
              float* __restrict__ out)
{
  __shared__ float sred[4];
  __shared__ int cred[4];
  const int tid = threadIdx.x;
  float s = 0.f;
  int cnt = 0;
  for (int i = tid; i < BT; i += 256) {
    s += rowterm[i];
    cnt += (target[i] != IGNORE_INDEX) ? 1 : 0;
  }
#pragma unroll
  for (int d = 1; d < 64; d <<= 1) {
    s += __shfl_xor(s, d);
    cnt += __shfl_xor(cnt, d);
  }
  const int wid = tid >> 6, lane = tid & 63;
  if (lane == 0) { sred[wid] = s; cred[wid] = cnt; }
  __syncthreads();
  if (tid == 0) {
    const float st = sred[0] + sred[1] + sred[2] + sred[3];
    const int ct = cred[0] + cred[1] + cred[2] + cred[3];
    const float n = (float)((ct > 0) ? ct : 1);
    const float rs = rsw[0];
    float loss = (rs == 0.f) ? 0.f : (st / n) / rs;
    loss /= (float)gas[0];
    out[0] = loss;
  }
}

extern "C" void kernel_launch(void* const* d_in, const int* in_sizes, int n_in,
                              void* d_out, int out_size, void* d_ws, size_t ws_size,
                              hipStream_t stream)
{
  const float* Wt     = (const float*)d_in[0];  // lin_weight (V,H)
  const float* X      = (const float*)d_in[1];  // _input (BT,H)
  const int*   target = (const int*)d_in[2];
  const float* bias   = (const float*)d_in[3];
  const float* lw     = (const float*)d_in[4];
  const float* rsw    = (const float*)d_in[5];
  const int*   gas    = (const int*)d_in[6];
  float* out = (float*)d_out;

  const size_t nW = (size_t)V * H, nX = (size_t)BT * H;

  __bf16* Wb = (__bf16*)d_ws;
  __bf16* Xb = Wb + nW;
  float* pM = (float*)(Xb + nX);
  float* pS = pM + (size_t)BT * NCHUNK;
  float* gold = pS + (size_t)BT * NCHUNK;
  float* rowterm = gold + BT;

  convert_bf16<<<dim3(2048), dim3(256), 0, stream>>>(Wt, Wb, (int)(nW / 8));
  convert_bf16<<<dim3(256), dim3(256), 0, stream>>>(X, Xb, (int)(nX / 8));
  gemm_lse_pipe<<<dim3(MT2 * NT2), dim3(512), 0, stream>>>(Wb, Xb, target,
                                                           bias, pM, pS, gold);
  reduce_lse<<<dim3(BT / 4), dim3(256), 0, stream>>>(pM, pS, gold, target, lw,
                                                     rowterm);
  finalize<<<dim3(1), dim3(256), 0, stream>>>(rowterm, target, rsw, gas, out);
}

// Round 10
// 595.702 us; speedup vs baseline: 1.2499x; 1.1350x over previous
//
#include <hip/hip_runtime.h>
#include <hip/hip_bf16.h>
#include <math.h>

#define IGNORE_INDEX (-100)

constexpr int BT = 2048, H = 4096, V = 32000;
constexpr int BM = 256, BN = 256, BK = 64;
constexpr int KT = H / BK;            // 64 k-tiles
constexpr int MT2 = BT / BM;          // 8
constexpr int NT2 = V / BN;           // 125
constexpr int NCHUNK = NT2 * 4;       // 500 partial chunks/row (64 cols each)

typedef int   i32x4  __attribute__((ext_vector_type(4)));
typedef int   i32x8  __attribute__((ext_vector_type(8)));
typedef float f32x16 __attribute__((ext_vector_type(16)));

// e8m0 scale byte for 2^-7 (operands are pre-scaled by 2^7 at conversion)
#define SC8 120

__device__ __forceinline__ void gload_lds16(const char* g, char* l) {
  __builtin_amdgcn_global_load_lds(
      (const __attribute__((address_space(1))) unsigned int*)(g),
      (__attribute__((address_space(3))) unsigned int*)(l), 16, 0, 0);
}

#define BAR()        asm volatile("s_barrier" ::: "memory")
#define WAIT_VM(N)   asm volatile("s_waitcnt vmcnt(" #N ")" ::: "memory")

// ---------------------------------------------------------------------------
// fp32 -> fp8 e4m3 (OCP) bulk convert with x128 pre-scale
// ---------------------------------------------------------------------------
__global__ __launch_bounds__(256)
void convert_fp8(const float* __restrict__ src, char* __restrict__ dst,
                 int n8) {
  int i = blockIdx.x * blockDim.x + threadIdx.x;
  const int stride = gridDim.x * blockDim.x;
  for (; i < n8; i += stride) {
    const float4 f0 = ((const float4*)src)[2 * i];
    const float4 f1 = ((const float4*)src)[2 * i + 1];
    const float S = 128.f;
    int lo = 0, hi = 0;
    lo = __builtin_amdgcn_cvt_pk_fp8_f32(f0.x * S, f0.y * S, lo, false);
    lo = __builtin_amdgcn_cvt_pk_fp8_f32(f0.z * S, f0.w * S, lo, true);
    hi = __builtin_amdgcn_cvt_pk_fp8_f32(f1.x * S, f1.y * S, hi, false);
    hi = __builtin_amdgcn_cvt_pk_fp8_f32(f1.z * S, f1.w * S, hi, true);
    int2 v; v.x = lo; v.y = hi;
    ((int2*)dst)[i] = v;
  }
}

// ---------------------------------------------------------------------------
// 256x256 MX-fp8 GEMM: mfma_scale_f32_32x32x64_f8f6f4, uniform e8m0 scales.
// LDS: per operand [buf:2][256 rows][64 B] = 32KB -> 64KB total (2 blocks/CU).
// 16B-slot XOR swizzle s^=(row&3); staged linear-dest via pre-swizzled
// source (rule #21); frag read = 2 separate ds_read_b128 (bank-uniform).
// Schedule: 4 phases / 2 K-tiles, 1 stage-region + VM(2) + BAR per phase,
// reads post-BAR (compiler counted lgkm waits before MFMA).
//  Region audit (stage p vs last read q: reads(q) drain < MFMA(q) < BAR(q+1)
//  <= BAR(p-1) < stage(p), need p >= q+2):
//   B(b0) read P1 -> staged P3 ✓   A(b0) read P1,P2 -> staged P4 ✓
//   B(b1) read P3 -> staged P1' ✓  A(b1) read P3,P4 -> staged P2' ✓
//  DMA-drain: VM(2)@p (pre-BAR) drains the stages of p-2,p-1 in every wave;
//  BAR(p) then orders them before reads(p) -> cross-wave safe.
//  B-frags carried in regs across the tile's two phases (read once).
// ---------------------------------------------------------------------------
__global__ __launch_bounds__(512, 2)
void gemm_lse_fp8(const char* __restrict__ Wq,   // (V,H) fp8, pre-scaled x128
                  const char* __restrict__ Xq,   // (BT,H) fp8, pre-scaled x128
                  const int* __restrict__ target,
                  const float* __restrict__ bias,
                  float* __restrict__ pM, float* __restrict__ pS,
                  float* __restrict__ gold)
{
  __shared__ char As[32768];   // [buf:2][256][64]
  __shared__ char Bs[32768];

  const int tid  = threadIdx.x;
  const int lane = tid & 63;
  const int wid  = tid >> 6;
  const int wr   = wid >> 2;        // 0..1 : rows [wr*128, +128)
  const int wcol = wid & 3;         // 0..3 : cols [wcol*64, +64)

  // XCD swizzle: nwg = 1000 = 8*125, bijective
  const int bid = (int)blockIdx.x;
  const int swz = (bid & 7) * 125 + (bid >> 3);
  const int mt = swz & (MT2 - 1);
  const int nt = swz >> 3;
  const int m0 = mt * BM, n0 = nt * BN;

  const int l31 = lane & 31;
  const int h   = lane >> 5;        // k-half owner: k in [h*32, h*32+32)
  const int k3  = l31 & 3;          // row&3 (invariant under +32 row steps)
  const int s0  = ((2 * h) ^ k3) << 4;       // stored slot of k-bytes 0..15
  const int s1  = ((2 * h + 1) ^ k3) << 4;   // stored slot of k-bytes 16..31
  const int abase = (wr * 128 + l31) * 64;
  const int bbase = (wcol * 64 + l31) * 64;

  // staging: lane covers row (lane>>2), slot lane&3; source pre-swizzled
  const int srow  = lane >> 2;
  const int sslot = ((lane & 3) ^ (srow & 3)) << 4;

  const char* asrc = Xq + (size_t)(m0 + wid * 32 + srow) * H + sslot;
  const char* bsrc = Wq + (size_t)(n0 + wid * 32 + srow) * H + sslot;

  f32x16 acc[4][2] = {};
  i32x8 aF0, aF1, bF0, bF1;

#define STAGE_A(BUF, DT)                                                      \
  { gload_lds16(asrc + (DT) * BK,                                             \
                &As[(BUF) * 16384 + wid * 2048 + lane * 16]);                 \
    gload_lds16(asrc + (size_t)16 * H + (DT) * BK,                            \
                &As[(BUF) * 16384 + wid * 2048 + 1024 + lane * 16]); }

#define STAGE_B(BUF, DT)                                                      \
  { gload_lds16(bsrc + (DT) * BK,                                             \
                &Bs[(BUF) * 16384 + wid * 2048 + lane * 16]);                 \
    gload_lds16(bsrc + (size_t)16 * H + (DT) * BK,                            \
                &Bs[(BUF) * 16384 + wid * 2048 + 1024 + lane * 16]); }

#define RDA(DST, BUF, MI)                                                     \
  { i32x4 lo = *(const i32x4*)&As[(BUF) * 16384 + abase + (MI) * 2048 + s0];  \
    i32x4 hi = *(const i32x4*)&As[(BUF) * 16384 + abase + (MI) * 2048 + s1];  \
    DST[0] = lo[0]; DST[1] = lo[1]; DST[2] = lo[2]; DST[3] = lo[3];           \
    DST[4] = hi[0]; DST[5] = hi[1]; DST[6] = hi[2]; DST[7] = hi[3]; }

#define RDB(DST, BUF, NJ)                                                     \
  { i32x4 lo = *(const i32x4*)&Bs[(BUF) * 16384 + bbase + (NJ) * 2048 + s0];  \
    i32x4 hi = *(const i32x4*)&Bs[(BUF) * 16384 + bbase + (NJ) * 2048 + s1];  \
    DST[0] = lo[0]; DST[1] = lo[1]; DST[2] = lo[2]; DST[3] = lo[3];           \
    DST[4] = hi[0]; DST[5] = hi[1]; DST[6] = hi[2]; DST[7] = hi[3]; }

#define MFMA4(MH)                                                             \
  { __builtin_amdgcn_s_setprio(1);                                            \
    acc[(MH)*2+0][0] = __builtin_amdgcn_mfma_scale_f32_32x32x64_f8f6f4(       \
        aF0, bF0, acc[(MH)*2+0][0], 0, 0, 0, SC8, 0, SC8);                    \
    acc[(MH)*2+0][1] = __builtin_amdgcn_mfma_scale_f32_32x32x64_f8f6f4(       \
        aF0, bF1, acc[(MH)*2+0][1], 0, 0, 0, SC8, 0, SC8);                    \
    acc[(MH)*2+1][0] = __builtin_amdgcn_mfma_scale_f32_32x32x64_f8f6f4(       \
        aF1, bF0, acc[(MH)*2+1][0], 0, 0, 0, SC8, 0, SC8);                    \
    acc[(MH)*2+1][1] = __builtin_amdgcn_mfma_scale_f32_32x32x64_f8f6f4(       \
        aF1, bF1, acc[(MH)*2+1][1], 0, 0, 0, SC8, 0, SC8);                    \
    __builtin_amdgcn_s_setprio(0); }

  // ---- prologue: tile0 -> buf0 (4 loads in flight)
  STAGE_B(0, 0); STAGE_A(0, 0);

  // ---- main loop: 2 K-tiles/iter, 4 phases, 1 barrier each
  for (int t = 0; t <= KT - 4; t += 2) {
    // P1: stage B(b1)<-t+1; VM(2) drains b0's stages; compute (b0, mh0)
    STAGE_B(1, 1);
    WAIT_VM(2); BAR();
    RDA(aF0, 0, 0); RDA(aF1, 0, 1); RDB(bF0, 0, 0); RDB(bF1, 0, 1);
    MFMA4(0);
    // P2: stage A(b1)<-t+1; compute (b0, mh1)  [B carried in regs]
    STAGE_A(1, 1);
    WAIT_VM(2); BAR();
    RDA(aF0, 0, 2); RDA(aF1, 0, 3);
    MFMA4(1);
    // P3: stage B(b0)<-t+2; VM(2) drains b1's stages; compute (b1, mh0)
    STAGE_B(0, 2);
    WAIT_VM(2); BAR();
    RDA(aF0, 1, 0); RDA(aF1, 1, 1); RDB(bF0, 1, 0); RDB(bF1, 1, 1);
    MFMA4(0);
    // P4: stage A(b0)<-t+2; compute (b1, mh1)
    STAGE_A(0, 2);
    WAIT_VM(2); BAR();
    RDA(aF0, 1, 2); RDA(aF1, 1, 3);
    MFMA4(1);

    asrc += 2 * BK; bsrc += 2 * BK;
  }

  // ---- tail: tiles KT-2 (b0), KT-1 (b1)
  STAGE_B(1, 1);
  WAIT_VM(2); BAR();
  RDA(aF0, 0, 0); RDA(aF1, 0, 1); RDB(bF0, 0, 0); RDB(bF1, 0, 1);
  MFMA4(0);
  STAGE_A(1, 1);
  WAIT_VM(2); BAR();
  RDA(aF0, 0, 2); RDA(aF1, 0, 3);
  MFMA4(1);
  WAIT_VM(0); BAR();
  RDA(aF0, 1, 0); RDA(aF1, 1, 1); RDB(bF0, 1, 0); RDB(bF1, 1, 1);
  MFMA4(0);
  RDA(aF0, 1, 2); RDA(aF1, 1, 3);
  MFMA4(1);

#undef STAGE_A
#undef STAGE_B
#undef RDA
#undef RDB
#undef MFMA4

  // ---- epilogue (32x32 C/D: col=lane&31, row=(r&3)+8*(r>>2)+4*h) — r5-verified
  const int colbase = n0 + wcol * 64;
  float bv[2];
#pragma unroll
  for (int nj = 0; nj < 2; ++nj) bv[nj] = bias[colbase + nj * 32 + l31];

  const int chunk = nt * 4 + wcol;
#pragma unroll
  for (int mi = 0; mi < 4; ++mi) {
#pragma unroll
    for (int r = 0; r < 16; ++r) {
      const int row = m0 + wr * 128 + mi * 32 + (r & 3) + 8 * (r >> 2) + 4 * h;
      const float v0 = acc[mi][0][r] + bv[0];
      const float v1 = acc[mi][1][r] + bv[1];
      float mx = fmaxf(v0, v1);
#pragma unroll
      for (int d = 1; d < 32; d <<= 1) mx = fmaxf(mx, __shfl_xor(mx, d));
      float s = expf(v0 - mx) + expf(v1 - mx);
#pragma unroll
      for (int d = 1; d < 32; d <<= 1) s += __shfl_xor(s, d);
      if (l31 == 0) {
        pM[(size_t)row * NCHUNK + chunk] = mx;
        pS[(size_t)row * NCHUNK + chunk] = s;
      }
      const int t = target[row];
      const int d0 = t - colbase;
      if (d0 >= 0 && d0 < 64 && l31 == (d0 & 31)) {
        gold[row] = (d0 >> 5) ? v1 : v0;
      }
    }
  }
}

// one wave per row: combine 500 (max, sumexp) chunks -> rowterm
__global__ __launch_bounds__(256)
void reduce_lse(const float* __restrict__ pM, const float* __restrict__ pS,
                const float* __restrict__ gold, const int* __restrict__ target,
                const float* __restrict__ lw, float* __restrict__ rowterm)
{
  const int wid = threadIdx.x >> 6, lane = threadIdx.x & 63;
  const int row = blockIdx.x * 4 + wid;
  if (row >= BT) return;
  const float* pm = pM + (size_t)row * NCHUNK;
  const float* ps = pS + (size_t)row * NCHUNK;
  float m = -INFINITY;
  for (int c2 = lane; c2 < NCHUNK; c2 += 64) m = fmaxf(m, pm[c2]);
#pragma unroll
  for (int d = 1; d < 64; d <<= 1) m = fmaxf(m, __shfl_xor(m, d));
  float s = 0.f;
  for (int c2 = lane; c2 < NCHUNK; c2 += 64) s += ps[c2] * expf(pm[c2] - m);
#pragma unroll
  for (int d = 1; d < 64; d <<= 1) s += __shfl_xor(s, d);
  if (lane == 0) {
    const int t = target[row];
    float term = 0.f;
    if (t != IGNORE_INDEX) term = (m + logf(s) - gold[row]) * lw[row];
    rowterm[row] = term;
  }
}

// single-block deterministic finalize
__global__ __launch_bounds__(256)
void finalize(const float* __restrict__ rowterm, const int* __restrict__ target,
              const float* __restrict__ rsw, const int* __restrict__ gas,
              float* __restrict__ out)
{
  __shared__ float sred[4];
  __shared__ int cred[4];
  const int tid = threadIdx.x;
  float s = 0.f;
  int cnt = 0;
  for (int i = tid; i < BT; i += 256) {
    s += rowterm[i];
    cnt += (target[i] != IGNORE_INDEX) ? 1 : 0;
  }
#pragma unroll
  for (int d = 1; d < 64; d <<= 1) {
    s += __shfl_xor(s, d);
    cnt += __shfl_xor(cnt, d);
  }
  const int wid = tid >> 6, lane = tid & 63;
  if (lane == 0) { sred[wid] = s; cred[wid] = cnt; }
  __syncthreads();
  if (tid == 0) {
    const float st = sred[0] + sred[1] + sred[2] + sred[3];
    const int ct = cred[0] + cred[1] + cred[2] + cred[3];
    const float n = (float)((ct > 0) ? ct : 1);
    const float rs = rsw[0];
    float loss = (rs == 0.f) ? 0.f : (st / n) / rs;
    loss /= (float)gas[0];
    out[0] = loss;
  }
}

extern "C" void kernel_launch(void* const* d_in, const int* in_sizes, int n_in,
                              void* d_out, int out_size, void* d_ws, size_t ws_size,
                              hipStream_t stream)
{
  const float* Wt     = (const float*)d_in[0];  // lin_weight (V,H)
  const float* X      = (const float*)d_in[1];  // _input (BT,H)
  const int*   target = (const int*)d_in[2];
  const float* bias   = (const float*)d_in[3];
  const float* lw     = (const float*)d_in[4];
  const float* rsw    = (const float*)d_in[5];
  const int*   gas    = (const int*)d_in[6];
  float* out = (float*)d_out;

  const size_t nW = (size_t)V * H, nX = (size_t)BT * H;

  char* Wq = (char*)d_ws;                       // V*H fp8
  char* Xq = Wq + nW;                           // BT*H fp8
  float* pM = (float*)(Xq + nX);
  float* pS = pM + (size_t)BT * NCHUNK;
  float* gold = pS + (size_t)BT * NCHUNK;
  float* rowterm = gold + BT;

  convert_fp8<<<dim3(2048), dim3(256), 0, stream>>>(Wt, Wq, (int)(nW / 8));
  convert_fp8<<<dim3(256), dim3(256), 0, stream>>>(X, Xq, (int)(nX / 8));
  gemm_lse_fp8<<<dim3(MT2 * NT2), dim3(512), 0, stream>>>(Wq, Xq, target,
                                                          bias, pM, pS, gold);
  reduce_lse<<<dim3(BT / 4), dim3(256), 0, stream>>>(pM, pS, gold, target, lw,
                                                     rowterm);
  finalize<<<dim3(1), dim3(256), 0, stream>>>(rowterm, target, rsw, gas, out);
}

// Round 11
// 548.745 us; speedup vs baseline: 1.3569x; 1.0856x over previous
//
#include <hip/hip_runtime.h>
#include <hip/hip_bf16.h>
#include <math.h>

#define IGNORE_INDEX (-100)

constexpr int BT = 2048, H = 4096, V = 32000;
constexpr int BM = 256, BN = 256, BK = 64;
constexpr int KT = H / BK;            // 64 k-tiles
constexpr int MT2 = BT / BM;          // 8
constexpr int NT2 = V / BN;           // 125
constexpr int NCHUNK = NT2 * 4;       // 500 partial chunks/row (64 cols each)

typedef int   i32x4  __attribute__((ext_vector_type(4)));
typedef int   i32x8  __attribute__((ext_vector_type(8)));
typedef float f32x16 __attribute__((ext_vector_type(16)));

// e8m0 scale byte for 2^-7 (operands are pre-scaled by 2^7 at conversion)
#define SC8 120

__device__ __forceinline__ void gload_lds16(const char* g, char* l) {
  __builtin_amdgcn_global_load_lds(
      (const __attribute__((address_space(1))) unsigned int*)(g),
      (__attribute__((address_space(3))) unsigned int*)(l), 16, 0, 0);
}

#define BAR()        asm volatile("s_barrier" ::: "memory")
#define WAIT_VM(N)   asm volatile("s_waitcnt vmcnt(" #N ")" ::: "memory")

// ---------------------------------------------------------------------------
// fp32 -> fp8 e4m3 (OCP) bulk convert with x128 pre-scale
// ---------------------------------------------------------------------------
__global__ __launch_bounds__(256)
void convert_fp8(const float* __restrict__ src, char* __restrict__ dst,
                 int n8) {
  int i = blockIdx.x * blockDim.x + threadIdx.x;
  const int stride = gridDim.x * blockDim.x;
  for (; i < n8; i += stride) {
    const float4 f0 = ((const float4*)src)[2 * i];
    const float4 f1 = ((const float4*)src)[2 * i + 1];
    const float S = 128.f;
    int lo = 0, hi = 0;
    lo = __builtin_amdgcn_cvt_pk_fp8_f32(f0.x * S, f0.y * S, lo, false);
    lo = __builtin_amdgcn_cvt_pk_fp8_f32(f0.z * S, f0.w * S, lo, true);
    hi = __builtin_amdgcn_cvt_pk_fp8_f32(f1.x * S, f1.y * S, hi, false);
    hi = __builtin_amdgcn_cvt_pk_fp8_f32(f1.z * S, f1.w * S, hi, true);
    int2 v; v.x = lo; v.y = hi;
    ((int2*)dst)[i] = v;
  }
}

// ---------------------------------------------------------------------------
// 256x256 MX-fp8 GEMM: mfma_scale_f32_32x32x64_f8f6f4, uniform e8m0 scales.
// LDS: per operand [buf:2][256 rows][64 B] = 32KB -> 64KB total (2 blocks/CU).
// SWIZZLE (fixed r11): stored 16B-slot(row, q) = q ^ ((row>>1)&3).
//   Bank-window position(row,slot) = (row&1)*4 + slot; with (row>>1)&3 in the
//   XOR, position is bijective over row mod 8 -> every hardware oct-group
//   (8 lanes x 16B = 128B) covers all 32 banks. (r10's (row&3) had period-4
//   positions -> 7.4e7 conflicts.)
// Staged linear-dest via pre-swizzled source quad (lane&3)^((lane>>3)&3)
// (rule #21: write-side permutation == read-side permutation).
// Schedule: 4 phases / 2 K-tiles, 1 stage-region + VM(2) + BAR per phase,
// reads post-BAR; region audit unchanged from r10 (verified, passed).
// ---------------------------------------------------------------------------
__global__ __launch_bounds__(512, 2)
void gemm_lse_fp8(const char* __restrict__ Wq,   // (V,H) fp8, pre-scaled x128
                  const char* __restrict__ Xq,   // (BT,H) fp8, pre-scaled x128
                  const int* __restrict__ target,
                  const float* __restrict__ bias,
                  float* __restrict__ pM, float* __restrict__ pS,
                  float* __restrict__ gold)
{
  __shared__ char As[32768];   // [buf:2][256][64]
  __shared__ char Bs[32768];

  const int tid  = threadIdx.x;
  const int lane = tid & 63;
  const int wid  = tid >> 6;
  const int wr   = wid >> 2;        // 0..1 : rows [wr*128, +128)
  const int wcol = wid & 3;         // 0..3 : cols [wcol*64, +64)

  // XCD swizzle: nwg = 1000 = 8*125, bijective
  const int bid = (int)blockIdx.x;
  const int swz = (bid & 7) * 125 + (bid >> 3);
  const int mt = swz & (MT2 - 1);
  const int nt = swz >> 3;
  const int m0 = mt * BM, n0 = nt * BN;

  const int l31 = lane & 31;
  const int h   = lane >> 5;        // k-half owner: k in [h*32, h*32+32)
  const int r2  = (l31 >> 1) & 3;   // (row>>1)&3 (invariant under +8 rows)
  const int s0  = ((2 * h) ^ r2) << 4;       // stored slot of k-bytes 0..15
  const int s1  = ((2 * h + 1) ^ r2) << 4;   // stored slot of k-bytes 16..31
  const int abase = (wr * 128 + l31) * 64;
  const int bbase = (wcol * 64 + l31) * 64;

  // staging: lane covers row (lane>>2), slot lane&3; source pre-swizzled:
  // q = slot ^ ((row>>1)&3) = (lane&3) ^ ((lane>>3)&3)
  const int srow  = lane >> 2;
  const int sslot = ((lane & 3) ^ ((lane >> 3) & 3)) << 4;

  const char* asrc = Xq + (size_t)(m0 + wid * 32 + srow) * H + sslot;
  const char* bsrc = Wq + (size_t)(n0 + wid * 32 + srow) * H + sslot;

  f32x16 acc[4][2] = {};
  i32x8 aF0, aF1, bF0, bF1;

#define STAGE_A(BUF, DT)                                                      \
  { gload_lds16(asrc + (DT) * BK,                                             \
                &As[(BUF) * 16384 + wid * 2048 + lane * 16]);                 \
    gload_lds16(asrc + (size_t)16 * H + (DT) * BK,                            \
                &As[(BUF) * 16384 + wid * 2048 + 1024 + lane * 16]); }

#define STAGE_B(BUF, DT)                                                      \
  { gload_lds16(bsrc + (DT) * BK,                                             \
                &Bs[(BUF) * 16384 + wid * 2048 + lane * 16]);                 \
    gload_lds16(bsrc + (size_t)16 * H + (DT) * BK,                            \
                &Bs[(BUF) * 16384 + wid * 2048 + 1024 + lane * 16]); }

#define RDA(DST, BUF, MI)                                                     \
  { i32x4 lo = *(const i32x4*)&As[(BUF) * 16384 + abase + (MI) * 2048 + s0];  \
    i32x4 hi = *(const i32x4*)&As[(BUF) * 16384 + abase + (MI) * 2048 + s1];  \
    DST[0] = lo[0]; DST[1] = lo[1]; DST[2] = lo[2]; DST[3] = lo[3];           \
    DST[4] = hi[0]; DST[5] = hi[1]; DST[6] = hi[2]; DST[7] = hi[3]; }

#define RDB(DST, BUF, NJ)                                                     \
  { i32x4 lo = *(const i32x4*)&Bs[(BUF) * 16384 + bbase + (NJ) * 2048 + s0];  \
    i32x4 hi = *(const i32x4*)&Bs[(BUF) * 16384 + bbase + (NJ) * 2048 + s1];  \
    DST[0] = lo[0]; DST[1] = lo[1]; DST[2] = lo[2]; DST[3] = lo[3];           \
    DST[4] = hi[0]; DST[5] = hi[1]; DST[6] = hi[2]; DST[7] = hi[3]; }

#define MFMA4(MH)                                                             \
  { __builtin_amdgcn_s_setprio(1);                                            \
    acc[(MH)*2+0][0] = __builtin_amdgcn_mfma_scale_f32_32x32x64_f8f6f4(       \
        aF0, bF0, acc[(MH)*2+0][0], 0, 0, 0, SC8, 0, SC8);                    \
    acc[(MH)*2+0][1] = __builtin_amdgcn_mfma_scale_f32_32x32x64_f8f6f4(       \
        aF0, bF1, acc[(MH)*2+0][1], 0, 0, 0, SC8, 0, SC8);                    \
    acc[(MH)*2+1][0] = __builtin_amdgcn_mfma_scale_f32_32x32x64_f8f6f4(       \
        aF1, bF0, acc[(MH)*2+1][0], 0, 0, 0, SC8, 0, SC8);                    \
    acc[(MH)*2+1][1] = __builtin_amdgcn_mfma_scale_f32_32x32x64_f8f6f4(       \
        aF1, bF1, acc[(MH)*2+1][1], 0, 0, 0, SC8, 0, SC8);                    \
    __builtin_amdgcn_s_setprio(0); }

  // ---- prologue: tile0 -> buf0 (4 loads in flight)
  STAGE_B(0, 0); STAGE_A(0, 0);

  // ---- main loop: 2 K-tiles/iter, 4 phases, 1 barrier each
  for (int t = 0; t <= KT - 4; t += 2) {
    // P1: stage B(b1)<-t+1; VM(2) drains b0's stages; compute (b0, mh0)
    STAGE_B(1, 1);
    WAIT_VM(2); BAR();
    RDA(aF0, 0, 0); RDA(aF1, 0, 1); RDB(bF0, 0, 0); RDB(bF1, 0, 1);
    MFMA4(0);
    // P2: stage A(b1)<-t+1; compute (b0, mh1)  [B carried in regs]
    STAGE_A(1, 1);
    WAIT_VM(2); BAR();
    RDA(aF0, 0, 2); RDA(aF1, 0, 3);
    MFMA4(1);
    // P3: stage B(b0)<-t+2; VM(2) drains b1's stages; compute (b1, mh0)
    STAGE_B(0, 2);
    WAIT_VM(2); BAR();
    RDA(aF0, 1, 0); RDA(aF1, 1, 1); RDB(bF0, 1, 0); RDB(bF1, 1, 1);
    MFMA4(0);
    // P4: stage A(b0)<-t+2; compute (b1, mh1)
    STAGE_A(0, 2);
    WAIT_VM(2); BAR();
    RDA(aF0, 1, 2); RDA(aF1, 1, 3);
    MFMA4(1);

    asrc += 2 * BK; bsrc += 2 * BK;
  }

  // ---- tail: tiles KT-2 (b0), KT-1 (b1)
  STAGE_B(1, 1);
  WAIT_VM(2); BAR();
  RDA(aF0, 0, 0); RDA(aF1, 0, 1); RDB(bF0, 0, 0); RDB(bF1, 0, 1);
  MFMA4(0);
  STAGE_A(1, 1);
  WAIT_VM(2); BAR();
  RDA(aF0, 0, 2); RDA(aF1, 0, 3);
  MFMA4(1);
  WAIT_VM(0); BAR();
  RDA(aF0, 1, 0); RDA(aF1, 1, 1); RDB(bF0, 1, 0); RDB(bF1, 1, 1);
  MFMA4(0);
  RDA(aF0, 1, 2); RDA(aF1, 1, 3);
  MFMA4(1);

#undef STAGE_A
#undef STAGE_B
#undef RDA
#undef RDB
#undef MFMA4

  // ---- epilogue (32x32 C/D: col=lane&31, row=(r&3)+8*(r>>2)+4*h) — verified
  const int colbase = n0 + wcol * 64;
  float bv[2];
#pragma unroll
  for (int nj = 0; nj < 2; ++nj) bv[nj] = bias[colbase + nj * 32 + l31];

  const int chunk = nt * 4 + wcol;
#pragma unroll
  for (int mi = 0; mi < 4; ++mi) {
#pragma unroll
    for (int r = 0; r < 16; ++r) {
      const int row = m0 + wr * 128 + mi * 32 + (r & 3) + 8 * (r >> 2) + 4 * h;
      const float v0 = acc[mi][0][r] + bv[0];
      const float v1 = acc[mi][1][r] + bv[1];
      float mx = fmaxf(v0, v1);
#pragma unroll
      for (int d = 1; d < 32; d <<= 1) mx = fmaxf(mx, __shfl_xor(mx, d));
      float s = expf(v0 - mx) + expf(v1 - mx);
#pragma unroll
      for (int d = 1; d < 32; d <<= 1) s += __shfl_xor(s, d);
      if (l31 == 0) {
        pM[(size_t)row * NCHUNK + chunk] = mx;
        pS[(size_t)row * NCHUNK + chunk] = s;
      }
      const int t = target[row];
      const int d0 = t - colbase;
      if (d0 >= 0 && d0 < 64 && l31 == (d0 & 31)) {
        gold[row] = (d0 >> 5) ? v1 : v0;
      }
    }
  }
}

// one wave per row: combine 500 (max, sumexp) chunks -> rowterm
__global__ __launch_bounds__(256)
void reduce_lse(const float* __restrict__ pM, const float* __restrict__ pS,
                const float* __restrict__ gold, const int* __restrict__ target,
                const float* __restrict__ lw, float* __restrict__ rowterm)
{
  const int wid = threadIdx.x >> 6, lane = threadIdx.x & 63;
  const int row = blockIdx.x * 4 + wid;
  if (row >= BT) return;
  const float* pm = pM + (size_t)row * NCHUNK;
  const float* ps = pS + (size_t)row * NCHUNK;
  float m = -INFINITY;
  for (int c2 = lane; c2 < NCHUNK; c2 += 64) m = fmaxf(m, pm[c2]);
#pragma unroll
  for (int d = 1; d < 64; d <<= 1) m = fmaxf(m, __shfl_xor(m, d));
  float s = 0.f;
  for (int c2 = lane; c2 < NCHUNK; c2 += 64) s += ps[c2] * expf(pm[c2] - m);
#pragma unroll
  for (int d = 1; d < 64; d <<= 1) s += __shfl_xor(s, d);
  if (lane == 0) {
    const int t = target[row];
    float term = 0.f;
    if (t != IGNORE_INDEX) term = (m + logf(s) - gold[row]) * lw[row];
    rowterm[row] = term;
  }
}

// single-block deterministic finalize
__global__ __launch_bounds__(256)
void finalize(const float* __restrict__ rowterm, const int* __restrict__ target,
              const float* __restrict__ rsw, const int* __restrict__ gas,
              float* __restrict__ out)
{
  __shared__ float sred[4];
  __shared__ int cred[4];
  const int tid = threadIdx.x;
  float s = 0.f;
  int cnt = 0;
  for (int i = tid; i < BT; i += 256) {
    s += rowterm[i];
    cnt += (target[i] != IGNORE_INDEX) ? 1 : 0;
  }
#pragma unroll
  for (int d = 1; d < 64; d <<= 1) {
    s += __shfl_xor(s, d);
    cnt += __shfl_xor(cnt, d);
  }
  const int wid = tid >> 6, lane = tid & 63;
  if (lane == 0) { sred[wid] = s; cred[wid] = cnt; }
  __syncthreads();
  if (tid == 0) {
    const float st = sred[0] + sred[1] + sred[2] + sred[3];
    const int ct = cred[0] + cred[1] + cred[2] + cred[3];
    const float n = (float)((ct > 0) ? ct : 1);
    const float rs = rsw[0];
    float loss = (rs == 0.f) ? 0.f : (st / n) / rs;
    loss /= (float)gas[0];
    out[0] = loss;
  }
}

extern "C" void kernel_launch(void* const* d_in, const int* in_sizes, int n_in,
                              void* d_out, int out_size, void* d_ws, size_t ws_size,
                              hipStream_t stream)
{
  const float* Wt     = (const float*)d_in[0];  // lin_weight (V,H)
  const float* X      = (const float*)d_in[1];  // _input (BT,H)
  const int*   target = (const int*)d_in[2];
  const float* bias   = (const float*)d_in[3];
  const float* lw     = (const float*)d_in[4];
  const float* rsw    = (const float*)d_in[5];
  const int*   gas    = (const int*)d_in[6];
  float* out = (float*)d_out;

  const size_t nW = (size_t)V * H, nX = (size_t)BT * H;

  char* Wq = (char*)d_ws;                       // V*H fp8
  char* Xq = Wq + nW;                           // BT*H fp8
  float* pM = (float*)(Xq + nX);
  float* pS = pM + (size_t)BT * NCHUNK;
  float* gold = pS + (size_t)BT * NCHUNK;
  float* rowterm = gold + BT;

  convert_fp8<<<dim3(2048), dim3(256), 0, stream>>>(Wt, Wq, (int)(nW / 8));
  convert_fp8<<<dim3(256), dim3(256), 0, stream>>>(X, Xq, (int)(nX / 8));
  gemm_lse_fp8<<<dim3(MT2 * NT2), dim3(512), 0, stream>>>(Wq, Xq, target,
                                                          bias, pM, pS, gold);
  reduce_lse<<<dim3(BT / 4), dim3(256), 0, stream>>>(pM, pS, gold, target, lw,
                                                     rowterm);
  finalize<<<dim3(1), dim3(256), 0, stream>>>(rowterm, target, rsw, gas, out);
}